// Round 8
// baseline (337.757 us; speedup 1.0000x reference)
//
#include <hip/hip_runtime.h>
#include <math.h>

#define NB 8192      // batch rows
#define NC 1000      // classes
#define NF4 250      // NC / 4 float4s per row

// ws layout (floats, stride NB):
//  [0..4]   margin per branch
//  [5..9]   gathered (raw) per branch
//  [10..14] KD per branch
//  [15]     CE
//  [16]     row min of gathered over 4 real teachers
//  [17]     row max of row-maxes over 4 real teachers

#define LOG2E 1.4426950408889634f
#define LN2   0.6931471805599453f
#define K20C  (LOG2E / 20.0f)

__device__ __forceinline__ float fexp2(float x) { return __builtin_amdgcn_exp2f(x); }
__device__ __forceinline__ float flog2(float x) { return __builtin_amdgcn_logf(x); }

// Explicit waits, each fenced with sched_barrier(0) (guide rule 18).
#define VMWAIT0                                          \
  asm volatile("s_waitcnt vmcnt(0)" ::: "memory");       \
  __builtin_amdgcn_sched_barrier(0)
#define LGKM0                                            \
  asm volatile("s_waitcnt lgkmcnt(0)" ::: "memory");     \
  __builtin_amdgcn_sched_barrier(0)

// Direct global->LDS (zero VGPR payload, cannot be sunk/spilled).
typedef const __attribute__((address_space(1))) unsigned int gu32;
typedef __attribute__((address_space(3))) unsigned int lu32;
__device__ __forceinline__ void stage16(const void* g, void* l) {
  __builtin_amdgcn_global_load_lds((gu32*)g, (lu32*)l, 16, 0, 0);
}

// ---------------- DPP wave reductions (VALU pipe, not DS) ----------------
template <int CTRL>
__device__ __forceinline__ float dpp_mov(float v, float ident) {
  return __uint_as_float((unsigned)__builtin_amdgcn_update_dpp(
      (int)__float_as_uint(ident), (int)__float_as_uint(v), CTRL, 0xF, 0xF,
      false));
}

__device__ __forceinline__ float dppredsum(float v) {
  v += dpp_mov<0x111>(v, 0.f);
  v += dpp_mov<0x112>(v, 0.f);
  v += dpp_mov<0x114>(v, 0.f);
  v += dpp_mov<0x118>(v, 0.f);
  v += dpp_mov<0x142>(v, 0.f);
  v += dpp_mov<0x143>(v, 0.f);
  return v;  // lane 63 = full sum
}

__device__ __forceinline__ void dppredtop2(float& t1, float& t2) {
  const float NI = -INFINITY;
#define T2STEP(C)                                   \
  {                                                 \
    float i1 = dpp_mov<C>(t1, NI);                  \
    float i2 = dpp_mov<C>(t2, NI);                  \
    t2 = fmaxf(fmaxf(t2, i2), fminf(t1, i1));       \
    t1 = fmaxf(t1, i1);                             \
  }
  T2STEP(0x111) T2STEP(0x112) T2STEP(0x114) T2STEP(0x118)
  T2STEP(0x142) T2STEP(0x143)
#undef T2STEP
  // lane 63 = (max, runner-up)
}

// shfl butterfly helpers (k_final): result lands in ALL lanes
__device__ __forceinline__ float wredsum(float v) {
#pragma unroll
  for (int m = 32; m >= 1; m >>= 1) v += __shfl_xor(v, m, 64);
  return v;
}
__device__ __forceinline__ float wredmax(float v) {
#pragma unroll
  for (int m = 32; m >= 1; m >>= 1) v = fmaxf(v, __shfl_xor(v, m, 64));
  return v;
}
__device__ __forceinline__ float wredmin(float v) {
#pragma unroll
  for (int m = 32; m >= 1; m >>= 1) v = fminf(v, __shfl_xor(v, m, 64));
  return v;
}
__device__ __forceinline__ float f4get(const float4& v, int e) {
  return e == 0 ? v.x : e == 1 ? v.y : e == 2 ? v.z : v.w;
}
__device__ __forceinline__ float& f4ref(float4& v, int e) {
  return e == 0 ? v.x : e == 1 ? v.y : e == 2 ? v.z : v.w;
}

// Per-matrix accumulate (4 elems, ONE branch) — cuts peak chunk regs 20->12.
// sum4 incrementally builds w0+w1+w2+w3; (((0+w0)+w1)+w2)+w3 is value-
// identical to the original ((w0+w1)+w2+w3) op order.
__device__ __forceinline__ void proc_mat(const float4& c, const float4& cs,
                                         float& t1, float& t2, float& Zm,
                                         float& S1m, float4& sum4) {
#pragma unroll
  for (int e = 0; e < 4; ++e) {
    float w = f4get(c, e);
    float wsv = f4get(cs, e);
    t2 = fmaxf(t2, fminf(t1, w));
    t1 = fmaxf(t1, w);
    float et = fexp2(w * K20C);
    Zm += et;
    S1m = fmaf(et, w - wsv, S1m);
    f4ref(sum4, e) += w;
  }
}

// ONE WAVE per row; 4 chunks of 5 KB via global_load_lds, single-buffered.
// R5/R6/R7 ledger: occupancy {33,78,48}%, spill {0,107,36} MB, time
// {65,93,88} µs — fabric proven at 2.7 TB/s (R6), clean-traffic low-occ at
// 65 µs (R5). The missing quadrant (high occ + no spill) needs true live
// set <= 64 VGPR, since any bound >=5 waves/EU caps there. This version:
// per-matrix chunk processing (20->12 chunk regs) + gathers deferred to the
// epilogue (frees 5 regs in body) -> live ~48. (256,8): 8 blocks/CU,
// LDS 8 x 20 KB = 160 KB (exact fit), 32 waves/CU.
__global__ __launch_bounds__(256, 8) void k_rowstats(
    const float* __restrict__ o1, const float* __restrict__ o2,
    const float* __restrict__ o3, const float* __restrict__ o4,
    const float* __restrict__ os, const int* __restrict__ tg,
    float* __restrict__ ws, float* __restrict__ out) {
  const int lane = threadIdx.x & 63;
  const int wv = threadIdx.x >> 6;          // 0..3
  const int row = (blockIdx.x << 2) + wv;   // grid = NB/4
  const size_t base = (size_t)row * NC;

  __shared__ float4 lds[4][5][64];          // [wave][matrix][lane] 20 KB

  // zero the output accumulator for k_final's atomics (runs strictly before)
  if (blockIdx.x == 0 && threadIdx.x == 0) out[0] = 0.0f;

  // tg early (1 int live; its vmcnt drain happens on an empty queue).
  // The 5 dependent gathers are deferred to the epilogue.
  const int target = tg[row];

#define STAGE(i)                                                          \
  do {                                                                    \
    int f_ = lane + ((i) << 6);                                           \
    if (f_ > NF4 - 1) f_ = NF4 - 1; /* clamp: dup load, masked at c3 */   \
    stage16((const float4*)(o1 + base) + f_, &lds[wv][0][0]);             \
    stage16((const float4*)(o2 + base) + f_, &lds[wv][1][0]);             \
    stage16((const float4*)(o3 + base) + f_, &lds[wv][2][0]);             \
    stage16((const float4*)(o4 + base) + f_, &lds[wv][3][0]);             \
    stage16((const float4*)(os + base) + f_, &lds[wv][4][0]);             \
  } while (0)

  STAGE(0);

  float t1[5], t2[5], Z[5], S1[5];
#pragma unroll
  for (int t = 0; t < 5; ++t) {
    t1[t] = -INFINITY; t2[t] = -INFINITY; Z[t] = 0.f; S1[t] = 0.f;
  }
  float Z1 = 0.f, Z20 = 0.f;

  // Per chunk: wait staging, read+process matrix-by-matrix (12 live regs),
  // drain LDS reads, refill buffer, then finish the mimic/student part from
  // sum4/rs while the next stage flies. All per-accumulator e-orders match
  // the previous version exactly (bit-identical outputs).
#define CHUNK(ACT, STAGE_STMT)                                            \
  do {                                                                    \
    VMWAIT0;                                                              \
    float4 rs_ = lds[wv][4][lane];                                        \
    float4 sum4_ = {0.f, 0.f, 0.f, 0.f};                                  \
    float4 cm_;                                                           \
    cm_ = lds[wv][0][lane];                                               \
    if (ACT) proc_mat(cm_, rs_, t1[0], t2[0], Z[0], S1[0], sum4_);        \
    cm_ = lds[wv][1][lane];                                               \
    if (ACT) proc_mat(cm_, rs_, t1[1], t2[1], Z[1], S1[1], sum4_);        \
    cm_ = lds[wv][2][lane];                                               \
    if (ACT) proc_mat(cm_, rs_, t1[2], t2[2], Z[2], S1[2], sum4_);        \
    cm_ = lds[wv][3][lane];                                               \
    if (ACT) proc_mat(cm_, rs_, t1[3], t2[3], Z[3], S1[3], sum4_);        \
    LGKM0; /* all reads of this buffer retired -> safe to overwrite */    \
    STAGE_STMT;                                                           \
    if (ACT) {                                                            \
      _Pragma("unroll")                                                   \
      for (int e = 0; e < 4; ++e) {                                       \
        float wsv = f4get(rs_, e);                                        \
        float wm = f4get(sum4_, e) * 0.25f;  /* mimic */                  \
        t2[4] = fmaxf(t2[4], fminf(t1[4], wm));                           \
        t1[4] = fmaxf(t1[4], wm);                                         \
        float et = fexp2(wm * K20C);                                      \
        Z[4] += et;                                                       \
        S1[4] = fmaf(et, wm - wsv, S1[4]);                                \
        Z1 += fexp2(wsv * LOG2E);                                         \
        Z20 += fexp2(wsv * K20C);                                         \
      }                                                                   \
    }                                                                     \
  } while (0)

  CHUNK(true, STAGE(1));
  CHUNK(true, STAGE(2));
  CHUNK(true, STAGE(3));
  CHUNK(lane < 58, );   // chunk 3: f = lane+192 < 250

  // gathers issued here: their latency hides under the ~320-instr DPP chain
  const float g1 = o1[base + target];
  const float g2 = o2[base + target];
  const float g3 = o3[base + target];
  const float g4 = o4[base + target];
  const float gs = os[base + target];

  // wave-level reductions on the VALU pipe (result in lane 63)
#pragma unroll
  for (int t = 0; t < 5; ++t) dppredtop2(t1[t], t2[t]);
#pragma unroll
  for (int t = 0; t < 5; ++t) { Z[t] = dppredsum(Z[t]); S1[t] = dppredsum(S1[t]); }
  Z1 = dppredsum(Z1);
  Z20 = dppredsum(Z20);

  if (lane == 63) {
    const float gm = ((g1 + g2) + g3 + g4) * 0.25f;  // same op order as wm
    float gg[5] = {g1, g2, g3, g4, gm};

    const float lse_s = flog2(Z20) * LN2;     // logsumexp(out_s/20), unshifted
    const float CE = flog2(Z1) * LN2 - gs;    // -log_softmax(out_s)[target]

#pragma unroll
    for (int t = 0; t < 5; ++t) {
      float lse_t = flog2(Z[t]) * LN2;
      float KD = 400.0f * (S1[t] / (20.0f * Z[t]) - lse_t + lse_s);
      float margin = (t1[t] == gg[t]) ? (t1[t] - t2[t]) : 0.0f;
      ws[(size_t)t * NB + row] = margin;
      ws[(size_t)(5 + t) * NB + row] = gg[t];
      ws[(size_t)(10 + t) * NB + row] = KD;
    }
    ws[(size_t)15 * NB + row] = CE;
    ws[(size_t)16 * NB + row] = fminf(fminf(g1, g2), fminf(g3, g4));
    ws[(size_t)17 * NB + row] = fmaxf(fmaxf(t1[0], t1[1]), fmaxf(t1[2], t1[3]));
  }
#undef STAGE
#undef CHUNK
}

// Fused minmax + loss: 128 blocks x 1 wave. Each block redundantly scans
// the 64 KB min/max columns (L2-resident) and processes 64 rows; butterfly
// reductions leave the result in all lanes. One atomicAdd per block.
__global__ __launch_bounds__(64) void k_final(const float* __restrict__ ws,
                                              float* __restrict__ out) {
  const int lane = threadIdx.x;             // 0..63, one wave

  float mn = INFINITY, mx = -INFINITY;
  const float4* mnp = (const float4*)(ws + (size_t)16 * NB);
  const float4* mxp = (const float4*)(ws + (size_t)17 * NB);
#pragma unroll
  for (int k = 0; k < 32; ++k) {            // 32 x 64 = 2048 = NB/4
    int r4 = lane + (k << 6);
    float4 a = mnp[r4];
    float4 b = mxp[r4];
    mn = fminf(mn, fminf(fminf(a.x, a.y), fminf(a.z, a.w)));
    mx = fmaxf(mx, fmaxf(fmaxf(b.x, b.y), fmaxf(b.z, b.w)));
  }
  mn = wredmin(mn);                         // all lanes
  mx = wredmax(mx);
  const float shift = (mn < 0.0f) ? (-mn + 1e-5f) : 0.0f;
  const float maxp = mx + shift;

  const int r = blockIdx.x * 64 + lane;     // 128 blocks x 64 = 8192 rows
  const float K6 = LOG2E / 6.0f;

  float m[5], e[5];
#pragma unroll
  for (int t = 0; t < 5; ++t) m[t] = ws[(size_t)t * NB + r];
  float pm = fmaxf(fmaxf(fmaxf(m[0], m[1]), fmaxf(m[2], m[3])), m[4]);
  float Zl = 0.0f;
#pragma unroll
  for (int t = 0; t < 5; ++t) { e[t] = fexp2((m[t] - pm) * K6); Zl += e[t]; }
  float ce = ws[(size_t)15 * NB + r];
  float rl = 0.0f;
#pragma unroll
  for (int t = 0; t < 5; ++t) {
    float g = ws[(size_t)(5 + t) * NB + r];
    float kd = ws[(size_t)(10 + t) * NB + r];
    float w2 = (g + shift) / maxp;
    float loss = (1.0f - w2) * ce + w2 * kd;
    rl += e[t] * loss;
  }
  float acc = wredsum(rl / Zl);
  if (lane == 0) atomicAdd(out, acc * (1.0f / 8192.0f));
}

extern "C" void kernel_launch(void* const* d_in, const int* in_sizes, int n_in,
                              void* d_out, int out_size, void* d_ws, size_t ws_size,
                              hipStream_t stream) {
  const float* o1 = (const float*)d_in[0];
  const float* o2 = (const float*)d_in[1];
  const float* o3 = (const float*)d_in[2];
  const float* o4 = (const float*)d_in[3];
  const float* os = (const float*)d_in[4];
  const int* tg = (const int*)d_in[5];
  float* ws = (float*)d_ws;
  float* out = (float*)d_out;

  k_rowstats<<<NB / 4, 256, 0, stream>>>(o1, o2, o3, o4, os, tg, ws, out);
  k_final<<<NB / 64, 64, 0, stream>>>(ws, out);
}

// Round 9
// 187.376 us; speedup vs baseline: 1.8026x; 1.8026x over previous
//
#include <hip/hip_runtime.h>
#include <math.h>

#define NB 8192      // batch rows
#define NC 1000      // classes
#define NF4 250      // NC / 4 float4s per row

// ws layout (floats, stride NB):
//  [0..4]   margin per branch
//  [5..9]   gathered (raw) per branch
//  [10..14] KD per branch
//  [15]     CE
//  [16]     row min of gathered over 4 real teachers
//  [17]     row max of row-maxes over 4 real teachers

#define LOG2E 1.4426950408889634f
#define LN2   0.6931471805599453f
#define K20C  (LOG2E / 20.0f)

__device__ __forceinline__ float fexp2(float x) { return __builtin_amdgcn_exp2f(x); }
__device__ __forceinline__ float flog2(float x) { return __builtin_amdgcn_logf(x); }

// Explicit waits, each fenced with sched_barrier(0) (guide rule 18).
#define VMWAIT0                                          \
  asm volatile("s_waitcnt vmcnt(0)" ::: "memory");       \
  __builtin_amdgcn_sched_barrier(0)
#define LGKM0                                            \
  asm volatile("s_waitcnt lgkmcnt(0)" ::: "memory");     \
  __builtin_amdgcn_sched_barrier(0)

// Direct global->LDS (zero VGPR payload, cannot be sunk/spilled).
typedef const __attribute__((address_space(1))) unsigned int gu32;
typedef __attribute__((address_space(3))) unsigned int lu32;
__device__ __forceinline__ void stage16(const void* g, void* l) {
  __builtin_amdgcn_global_load_lds((gu32*)g, (lu32*)l, 16, 0, 0);
}

// ---------------- DPP wave reductions (VALU pipe, not DS) ----------------
template <int CTRL>
__device__ __forceinline__ float dpp_mov(float v, float ident) {
  return __uint_as_float((unsigned)__builtin_amdgcn_update_dpp(
      (int)__float_as_uint(ident), (int)__float_as_uint(v), CTRL, 0xF, 0xF,
      false));
}

__device__ __forceinline__ float dppredsum(float v) {
  v += dpp_mov<0x111>(v, 0.f);
  v += dpp_mov<0x112>(v, 0.f);
  v += dpp_mov<0x114>(v, 0.f);
  v += dpp_mov<0x118>(v, 0.f);
  v += dpp_mov<0x142>(v, 0.f);
  v += dpp_mov<0x143>(v, 0.f);
  return v;  // lane 63 = full sum
}

__device__ __forceinline__ void dppredtop2(float& t1, float& t2) {
  const float NI = -INFINITY;
#define T2STEP(C)                                   \
  {                                                 \
    float i1 = dpp_mov<C>(t1, NI);                  \
    float i2 = dpp_mov<C>(t2, NI);                  \
    t2 = fmaxf(fmaxf(t2, i2), fminf(t1, i1));       \
    t1 = fmaxf(t1, i1);                             \
  }
  T2STEP(0x111) T2STEP(0x112) T2STEP(0x114) T2STEP(0x118)
  T2STEP(0x142) T2STEP(0x143)
#undef T2STEP
  // lane 63 = (max, runner-up)
}

// shfl butterfly helpers (k_final): result lands in ALL lanes
__device__ __forceinline__ float wredsum(float v) {
#pragma unroll
  for (int m = 32; m >= 1; m >>= 1) v += __shfl_xor(v, m, 64);
  return v;
}
__device__ __forceinline__ float wredmax(float v) {
#pragma unroll
  for (int m = 32; m >= 1; m >>= 1) v = fmaxf(v, __shfl_xor(v, m, 64));
  return v;
}
__device__ __forceinline__ float wredmin(float v) {
#pragma unroll
  for (int m = 32; m >= 1; m >>= 1) v = fminf(v, __shfl_xor(v, m, 64));
  return v;
}
__device__ __forceinline__ float f4get(const float4& v, int e) {
  return e == 0 ? v.x : e == 1 ? v.y : e == 2 ? v.z : v.w;
}
__device__ __forceinline__ float& f4ref(float4& v, int e) {
  return e == 0 ? v.x : e == 1 ? v.y : e == 2 ? v.z : v.w;
}

// Per-matrix accumulate (4 elems, ONE branch) — keeps peak chunk regs ~12.
// sum4 incrementally builds w0+w1+w2+w3; (((0+w0)+w1)+w2)+w3 is value-
// identical to the original ((w0+w1)+w2+w3) op order.
__device__ __forceinline__ void proc_mat(const float4& c, const float4& cs,
                                         float& t1, float& t2, float& Zm,
                                         float& S1m, float4& sum4) {
#pragma unroll
  for (int e = 0; e < 4; ++e) {
    float w = f4get(c, e);
    float wsv = f4get(cs, e);
    t2 = fmaxf(t2, fminf(t1, w));
    t1 = fmaxf(t1, w);
    float et = fexp2(w * K20C);
    Zm += et;
    S1m = fmaf(et, w - wsv, S1m);
    f4ref(sum4, e) += w;
  }
}

// ONE WAVE per row; 4 chunks of 5 KB via global_load_lds, single-buffered.
// R6/R7/R8 established the empirical law: hipcc's VGPR cap = ~256/min_waves
// (NOT 512/min_waves) -> any min-waves >= 5 under-allocates and spills
// (R8: cap 32, 450 MB spill writes). Fix: keep min_waves=4 (cap 64 >= live
// ~48 -> NO spill) and let RUNTIME occupancy follow actual usage: LDS
// 20 KB/block allows 8 blocks/CU and VGPR <= 64 allows 8 waves/SIMD ->
// 32 waves/CU theoretical. First config with high residency AND clean
// traffic (fabric proven to 3.6 TB/s at high occupancy, R8).
__global__ __launch_bounds__(256, 4) void k_rowstats(
    const float* __restrict__ o1, const float* __restrict__ o2,
    const float* __restrict__ o3, const float* __restrict__ o4,
    const float* __restrict__ os, const int* __restrict__ tg,
    float* __restrict__ ws, float* __restrict__ out) {
  const int lane = threadIdx.x & 63;
  const int wv = threadIdx.x >> 6;          // 0..3
  const int row = (blockIdx.x << 2) + wv;   // grid = NB/4
  const size_t base = (size_t)row * NC;

  __shared__ float4 lds[4][5][64];          // [wave][matrix][lane] 20 KB

  // zero the output accumulator for k_final's atomics (runs strictly before)
  if (blockIdx.x == 0 && threadIdx.x == 0) out[0] = 0.0f;

  // tg early (1 int live; its vmcnt drain happens on an empty queue).
  // The 5 dependent gathers are deferred to the epilogue.
  const int target = tg[row];

#define STAGE(i)                                                          \
  do {                                                                    \
    int f_ = lane + ((i) << 6);                                           \
    if (f_ > NF4 - 1) f_ = NF4 - 1; /* clamp: dup load, masked at c3 */   \
    stage16((const float4*)(o1 + base) + f_, &lds[wv][0][0]);             \
    stage16((const float4*)(o2 + base) + f_, &lds[wv][1][0]);             \
    stage16((const float4*)(o3 + base) + f_, &lds[wv][2][0]);             \
    stage16((const float4*)(o4 + base) + f_, &lds[wv][3][0]);             \
    stage16((const float4*)(os + base) + f_, &lds[wv][4][0]);             \
  } while (0)

  STAGE(0);

  float t1[5], t2[5], Z[5], S1[5];
#pragma unroll
  for (int t = 0; t < 5; ++t) {
    t1[t] = -INFINITY; t2[t] = -INFINITY; Z[t] = 0.f; S1[t] = 0.f;
  }
  float Z1 = 0.f, Z20 = 0.f;

  // Per chunk: wait staging, read+process matrix-by-matrix (~12 live regs),
  // drain LDS reads, refill buffer, then finish the mimic/student part from
  // sum4/rs while the next stage flies. All per-accumulator e-orders match
  // the verified version exactly (bit-identical outputs).
#define CHUNK(ACT, STAGE_STMT)                                            \
  do {                                                                    \
    VMWAIT0;                                                              \
    float4 rs_ = lds[wv][4][lane];                                        \
    float4 sum4_ = {0.f, 0.f, 0.f, 0.f};                                  \
    float4 cm_;                                                           \
    cm_ = lds[wv][0][lane];                                               \
    if (ACT) proc_mat(cm_, rs_, t1[0], t2[0], Z[0], S1[0], sum4_);        \
    cm_ = lds[wv][1][lane];                                               \
    if (ACT) proc_mat(cm_, rs_, t1[1], t2[1], Z[1], S1[1], sum4_);        \
    cm_ = lds[wv][2][lane];                                               \
    if (ACT) proc_mat(cm_, rs_, t1[2], t2[2], Z[2], S1[2], sum4_);        \
    cm_ = lds[wv][3][lane];                                               \
    if (ACT) proc_mat(cm_, rs_, t1[3], t2[3], Z[3], S1[3], sum4_);        \
    LGKM0; /* all reads of this buffer retired -> safe to overwrite */    \
    STAGE_STMT;                                                           \
    if (ACT) {                                                            \
      _Pragma("unroll")                                                   \
      for (int e = 0; e < 4; ++e) {                                       \
        float wsv = f4get(rs_, e);                                        \
        float wm = f4get(sum4_, e) * 0.25f;  /* mimic */                  \
        t2[4] = fmaxf(t2[4], fminf(t1[4], wm));                           \
        t1[4] = fmaxf(t1[4], wm);                                         \
        float et = fexp2(wm * K20C);                                      \
        Z[4] += et;                                                       \
        S1[4] = fmaf(et, wm - wsv, S1[4]);                                \
        Z1 += fexp2(wsv * LOG2E);                                         \
        Z20 += fexp2(wsv * K20C);                                         \
      }                                                                   \
    }                                                                     \
  } while (0)

  CHUNK(true, STAGE(1));
  CHUNK(true, STAGE(2));
  CHUNK(true, STAGE(3));
  CHUNK(lane < 58, );   // chunk 3: f = lane+192 < 250

  // gathers issued here: their latency hides under the ~320-instr DPP chain
  const float g1 = o1[base + target];
  const float g2 = o2[base + target];
  const float g3 = o3[base + target];
  const float g4 = o4[base + target];
  const float gs = os[base + target];

  // wave-level reductions on the VALU pipe (result in lane 63)
#pragma unroll
  for (int t = 0; t < 5; ++t) dppredtop2(t1[t], t2[t]);
#pragma unroll
  for (int t = 0; t < 5; ++t) { Z[t] = dppredsum(Z[t]); S1[t] = dppredsum(S1[t]); }
  Z1 = dppredsum(Z1);
  Z20 = dppredsum(Z20);

  if (lane == 63) {
    const float gm = ((g1 + g2) + g3 + g4) * 0.25f;  // same op order as wm
    float gg[5] = {g1, g2, g3, g4, gm};

    const float lse_s = flog2(Z20) * LN2;     // logsumexp(out_s/20), unshifted
    const float CE = flog2(Z1) * LN2 - gs;    // -log_softmax(out_s)[target]

#pragma unroll
    for (int t = 0; t < 5; ++t) {
      float lse_t = flog2(Z[t]) * LN2;
      float KD = 400.0f * (S1[t] / (20.0f * Z[t]) - lse_t + lse_s);
      float margin = (t1[t] == gg[t]) ? (t1[t] - t2[t]) : 0.0f;
      ws[(size_t)t * NB + row] = margin;
      ws[(size_t)(5 + t) * NB + row] = gg[t];
      ws[(size_t)(10 + t) * NB + row] = KD;
    }
    ws[(size_t)15 * NB + row] = CE;
    ws[(size_t)16 * NB + row] = fminf(fminf(g1, g2), fminf(g3, g4));
    ws[(size_t)17 * NB + row] = fmaxf(fmaxf(t1[0], t1[1]), fmaxf(t1[2], t1[3]));
  }
#undef STAGE
#undef CHUNK
}

// Fused minmax + loss: 128 blocks x 1 wave. Each block redundantly scans
// the 64 KB min/max columns (L2-resident) and processes 64 rows; butterfly
// reductions leave the result in all lanes. One atomicAdd per block.
__global__ __launch_bounds__(64) void k_final(const float* __restrict__ ws,
                                              float* __restrict__ out) {
  const int lane = threadIdx.x;             // 0..63, one wave

  float mn = INFINITY, mx = -INFINITY;
  const float4* mnp = (const float4*)(ws + (size_t)16 * NB);
  const float4* mxp = (const float4*)(ws + (size_t)17 * NB);
#pragma unroll
  for (int k = 0; k < 32; ++k) {            // 32 x 64 = 2048 = NB/4
    int r4 = lane + (k << 6);
    float4 a = mnp[r4];
    float4 b = mxp[r4];
    mn = fminf(mn, fminf(fminf(a.x, a.y), fminf(a.z, a.w)));
    mx = fmaxf(mx, fmaxf(fmaxf(b.x, b.y), fmaxf(b.z, b.w)));
  }
  mn = wredmin(mn);                         // all lanes
  mx = wredmax(mx);
  const float shift = (mn < 0.0f) ? (-mn + 1e-5f) : 0.0f;
  const float maxp = mx + shift;

  const int r = blockIdx.x * 64 + lane;     // 128 blocks x 64 = 8192 rows
  const float K6 = LOG2E / 6.0f;

  float m[5], e[5];
#pragma unroll
  for (int t = 0; t < 5; ++t) m[t] = ws[(size_t)t * NB + r];
  float pm = fmaxf(fmaxf(fmaxf(m[0], m[1]), fmaxf(m[2], m[3])), m[4]);
  float Zl = 0.0f;
#pragma unroll
  for (int t = 0; t < 5; ++t) { e[t] = fexp2((m[t] - pm) * K6); Zl += e[t]; }
  float ce = ws[(size_t)15 * NB + r];
  float rl = 0.0f;
#pragma unroll
  for (int t = 0; t < 5; ++t) {
    float g = ws[(size_t)(5 + t) * NB + r];
    float kd = ws[(size_t)(10 + t) * NB + r];
    float w2 = (g + shift) / maxp;
    float loss = (1.0f - w2) * ce + w2 * kd;
    rl += e[t] * loss;
  }
  float acc = wredsum(rl / Zl);
  if (lane == 0) atomicAdd(out, acc * (1.0f / 8192.0f));
}

extern "C" void kernel_launch(void* const* d_in, const int* in_sizes, int n_in,
                              void* d_out, int out_size, void* d_ws, size_t ws_size,
                              hipStream_t stream) {
  const float* o1 = (const float*)d_in[0];
  const float* o2 = (const float*)d_in[1];
  const float* o3 = (const float*)d_in[2];
  const float* o4 = (const float*)d_in[3];
  const float* os = (const float*)d_in[4];
  const int* tg = (const int*)d_in[5];
  float* ws = (float*)d_ws;
  float* out = (float*)d_out;

  k_rowstats<<<NB / 4, 256, 0, stream>>>(o1, o2, o3, o4, os, tg, ws, out);
  k_final<<<NB / 64, 64, 0, stream>>>(ws, out);
}